// Round 11
// baseline (1049.945 us; speedup 1.0000x reference)
//
#include <hip/hip_runtime.h>
#include <hip/hip_bf16.h>
#include <hip/hip_cooperative_groups.h>
#include <math.h>

namespace cg = cooperative_groups;

// GCN stack: 3x [GCNConv + ReLU] + MLP head (64->32 relu ->40) + log_softmax.
// R11: the 7-phase layer pipeline (gemm0,gather0,...,gemm2,gather2,head) is
// fused into ONE cooperative kernel with grid.sync() between phases —
// R10 accounting showed ~200us of the 462 unexplained by top-5 kernel time
// (launch gaps / hidden small kernels). 11 launches -> 5. ebuf packed to
// 4B/edge (src<<9 | dst&511). Gather body = R10 (4-deep unroll, bf16 rows,
// ~3.4 TB/s beyond-L2 fetch = measured fabric ceiling).

#define DIMF 64
#define NBA  200     // blocks for bucket count/scatter
#define BSH  9       // 512 nodes per bucket

// ---------------- CSR build (bucketed, packed ebuf) ----------------

__global__ __launch_bounds__(256) void bucket_count(
    const int* __restrict__ dst, int* __restrict__ partial, int E, int tile)
{
    __shared__ int h[256];
    int t = threadIdx.x;
    h[t] = 0;
    __syncthreads();
    int estart = blockIdx.x * tile;
    int eend = min(E, estart + tile);
    for (int e = estart + t; e < eend; e += 256)
        atomicAdd(&h[dst[e] >> BSH], 1);
    __syncthreads();
    partial[blockIdx.x * 256 + t] = h[t];
}

__global__ __launch_bounds__(256) void bucket_scan(
    const int* __restrict__ partial, int* __restrict__ bucket_off,
    int* __restrict__ gcursor, int nba)
{
    __shared__ int s[256];
    int t = threadIdx.x;
    int sum = 0;
    for (int b = 0; b < nba; b++) sum += partial[b * 256 + t];
    s[t] = sum;
    __syncthreads();
    for (int off = 1; off < 256; off <<= 1) {
        int v = (t >= off) ? s[t - off] : 0;
        __syncthreads();
        s[t] += v;
        __syncthreads();
    }
    int excl = s[t] - sum;
    bucket_off[t] = excl;
    gcursor[t] = excl;
    if (t == 255) bucket_off[256] = s[t];   // == E
}

__global__ __launch_bounds__(256) void bucket_scatter(
    const int* __restrict__ src, const int* __restrict__ dst,
    int* __restrict__ gcursor, unsigned int* __restrict__ ebuf, int E, int tile)
{
    __shared__ int h[256];
    int t = threadIdx.x;
    h[t] = 0;
    __syncthreads();
    int estart = blockIdx.x * tile;
    int eend = min(E, estart + tile);
    for (int e = estart + t; e < eend; e += 256)
        atomicAdd(&h[dst[e] >> BSH], 1);
    __syncthreads();
    h[t] = atomicAdd(&gcursor[t], h[t]);   // block-local cursor base
    __syncthreads();
    for (int e = estart + t; e < eend; e += 256) {
        int d = dst[e];
        int p = atomicAdd(&h[d >> BSH], 1);
        ebuf[p] = ((unsigned int)src[e] << BSH) | (unsigned int)(d & 511);
    }
}

__global__ __launch_bounds__(256) void bucket_csr(
    const unsigned int* __restrict__ ebuf, const int* __restrict__ bucket_off,
    int* __restrict__ row_start, int* __restrict__ csr_src,
    float* __restrict__ dinv, int n, int E)
{
    __shared__ int cnt[512];
    __shared__ int ps[256];
    int t = threadIdx.x;
    int blk = blockIdx.x;
    int node0 = blk << BSH;
    cnt[t] = 0; cnt[t + 256] = 0;
    __syncthreads();
    int bs = bucket_off[blk], be = bucket_off[blk + 1];
    for (int i = bs + t; i < be; i += 256)
        atomicAdd(&cnt[ebuf[i] & 511], 1);
    __syncthreads();
    int c0 = cnt[2 * t], c1 = cnt[2 * t + 1];
    ps[t] = c0 + c1;
    __syncthreads();
    for (int off = 1; off < 256; off <<= 1) {
        int v = (t >= off) ? ps[t - off] : 0;
        __syncthreads();
        ps[t] += v;
        __syncthreads();
    }
    int pexcl = ps[t] - (c0 + c1);
    int e0 = pexcl, e1 = pexcl + c0;
    int g0 = node0 + 2 * t, g1 = g0 + 1;
    if (g0 < n) { row_start[g0] = bs + e0; dinv[g0] = rsqrtf((float)c0 + 1.0f); }
    if (g1 < n) { row_start[g1] = bs + e1; dinv[g1] = rsqrtf((float)c1 + 1.0f); }
    __syncthreads();
    cnt[2 * t] = e0; cnt[2 * t + 1] = e1;    // cnt becomes local cursor
    __syncthreads();
    for (int i = bs + t; i < be; i += 256) {
        unsigned int pk = ebuf[i];
        int p = bs + atomicAdd(&cnt[pk & 511], 1);
        csr_src[p] = (int)(pk >> BSH);
    }
    if (blk == gridDim.x - 1 && t == 0) row_start[n] = E;
}

// ---------------- fused layer pipeline (cooperative) ----------------

struct FusedArgs {
    const float* x;
    const int* row_start;
    const int* csr_src;
    const float* dinv;
    const float* W0; const float* b0;
    const float* W1; const float* b1;
    const float* W2; const float* b2;
    const float* Wp1; const float* bp1;
    const float* Wp2; const float* bp2;
    float* out;
    __hip_bfloat16* hp;
    __hip_bfloat16* xbuf;
    int n;
};

__device__ __forceinline__ void gemm_compute_store(
    const float* __restrict__ Ws, const float (*__restrict__ Xs)[65],
    const float* __restrict__ dinv, __hip_bfloat16* __restrict__ hp,
    int row0, int col, int rbase, int n)
{
    float av[8];
#pragma unroll
    for (int rr = 0; rr < 8; rr++) av[rr] = 0.0f;
    for (int k = 0; k < 64; k++) {
        float w = Ws[k * 64 + col];
#pragma unroll
        for (int rr = 0; rr < 8; rr++)
            av[rr] = fmaf(Xs[rbase + rr][k], w, av[rr]);
    }
#pragma unroll
    for (int rr = 0; rr < 8; rr++) {
        int gr = row0 + rbase + rr;
        if (gr < n)
            hp[(size_t)gr * DIMF + col] = __float2bfloat16(av[rr] * dinv[gr]);
    }
}

__device__ void gemm_f32(const float* __restrict__ xin, const float* __restrict__ W,
                         const float* __restrict__ dinv, __hip_bfloat16* __restrict__ hp,
                         int n, float* Ws, float (*Xs)[65])
{
    int t = threadIdx.x;
    for (int i = t; i < 4096; i += 256) Ws[i] = W[i];
    __syncthreads();
    int col = t & 63, rbase = (t >> 6) * 8;
    int ntiles = (n + 31) >> 5;
    for (int tile = blockIdx.x; tile < ntiles; tile += gridDim.x) {
        int row0 = tile << 5;
        for (int i = t; i < 2048; i += 256) {
            int r = i >> 6, c = i & 63;
            int gr = row0 + r;
            Xs[r][c] = (gr < n) ? xin[(size_t)gr * DIMF + c] : 0.0f;
        }
        __syncthreads();
        gemm_compute_store(Ws, Xs, dinv, hp, row0, col, rbase, n);
        __syncthreads();
    }
}

__device__ void gemm_bf16(const unsigned int* __restrict__ xin,  // 32 uints/row
                          const float* __restrict__ W,
                          const float* __restrict__ dinv, __hip_bfloat16* __restrict__ hp,
                          int n, float* Ws, float (*Xs)[65])
{
    int t = threadIdx.x;
    for (int i = t; i < 4096; i += 256) Ws[i] = W[i];
    __syncthreads();
    int col = t & 63, rbase = (t >> 6) * 8;
    int ntiles = (n + 31) >> 5;
    for (int tile = blockIdx.x; tile < ntiles; tile += gridDim.x) {
        int row0 = tile << 5;
        {   // 256 threads x 8 feats = 32x64
            int r = t >> 3, c = (t & 7) << 3;
            int gr = row0 + r;
            if (gr < n) {
                uint4 v = *(const uint4*)(xin + (size_t)gr * 32 + (c >> 1));
                Xs[r][c + 0] = __uint_as_float(v.x << 16);
                Xs[r][c + 1] = __uint_as_float(v.x & 0xffff0000u);
                Xs[r][c + 2] = __uint_as_float(v.y << 16);
                Xs[r][c + 3] = __uint_as_float(v.y & 0xffff0000u);
                Xs[r][c + 4] = __uint_as_float(v.z << 16);
                Xs[r][c + 5] = __uint_as_float(v.z & 0xffff0000u);
                Xs[r][c + 6] = __uint_as_float(v.w << 16);
                Xs[r][c + 7] = __uint_as_float(v.w & 0xffff0000u);
            } else {
#pragma unroll
                for (int j = 0; j < 8; j++) Xs[r][c + j] = 0.0f;
            }
        }
        __syncthreads();
        gemm_compute_store(Ws, Xs, dinv, hp, row0, col, rbase, n);
        __syncthreads();
    }
}

// 8 nodes/wave, 8 lanes/node; 4-deep unroll, 4 accumulator banks; bf16 out.
__device__ void gather_phase(
    const unsigned int* __restrict__ hprime,  // bf16x2 packed, 32 uints/row
    const int* __restrict__ row_start, const int* __restrict__ csr_src,
    const float* __restrict__ dinv, const float* __restrict__ b,
    __hip_bfloat16* __restrict__ xout, int n)
{
    int wave = threadIdx.x >> 6;
    int lane = threadIdx.x & 63;
    int slot = lane >> 3;
    int uoff = (lane & 7) << 2;
    int ngroups = (n + 31) >> 5;          // 32 nodes per block-iteration
    for (int g = blockIdx.x; g < ngroups; g += gridDim.x) {
        int node = (g << 5) + (wave << 3) + slot;
        if (node >= n) continue;

        int rs = row_start[node];
        int re = row_start[node + 1];
        int deg = re - rs;

        float a0[8], a1[8], a2[8], a3[8];
#pragma unroll
        for (int i = 0; i < 8; i++) { a0[i] = 0.0f; a1[i] = 0.0f; a2[i] = 0.0f; a3[i] = 0.0f; }

#define ADDROW(a, v)                                                       \
        {                                                                  \
            a[0] += __uint_as_float((v).x << 16);                          \
            a[1] += __uint_as_float((v).x & 0xffff0000u);                  \
            a[2] += __uint_as_float((v).y << 16);                          \
            a[3] += __uint_as_float((v).y & 0xffff0000u);                  \
            a[4] += __uint_as_float((v).z << 16);                          \
            a[5] += __uint_as_float((v).z & 0xffff0000u);                  \
            a[6] += __uint_as_float((v).w << 16);                          \
            a[7] += __uint_as_float((v).w & 0xffff0000u);                  \
        }

        {   // self loop
            uint4 v = *(const uint4*)(hprime + (size_t)node * 32 + uoff);
            ADDROW(a0, v);
        }
        int k = 0;
        if (deg >= 4) {
            int i0 = csr_src[rs], i1 = csr_src[rs + 1];
            int i2 = csr_src[rs + 2], i3 = csr_src[rs + 3];
            for (; k + 4 <= deg; k += 4) {
                int m0 = (k + 4 < deg) ? csr_src[rs + k + 4] : 0;
                int m1 = (k + 5 < deg) ? csr_src[rs + k + 5] : 0;
                int m2 = (k + 6 < deg) ? csr_src[rs + k + 6] : 0;
                int m3 = (k + 7 < deg) ? csr_src[rs + k + 7] : 0;
                uint4 v0 = *(const uint4*)(hprime + (size_t)i0 * 32 + uoff);
                uint4 v1 = *(const uint4*)(hprime + (size_t)i1 * 32 + uoff);
                uint4 v2 = *(const uint4*)(hprime + (size_t)i2 * 32 + uoff);
                uint4 v3 = *(const uint4*)(hprime + (size_t)i3 * 32 + uoff);
                ADDROW(a0, v0);
                ADDROW(a1, v1);
                ADDROW(a2, v2);
                ADDROW(a3, v3);
                i0 = m0; i1 = m1; i2 = m2; i3 = m3;
            }
        }
        for (; k < deg; k++) {
            int idx = csr_src[rs + k];
            uint4 v = *(const uint4*)(hprime + (size_t)idx * 32 + uoff);
            ADDROW(a0, v);
        }
#undef ADDROW

        int f8 = uoff << 1;
        float dv = dinv[node];
        unsigned int pk[4];
#pragma unroll
        for (int j = 0; j < 4; j++) {
            float lo = fmaxf(fmaf(dv, a0[2*j]   + a1[2*j]   + a2[2*j]   + a3[2*j],   b[f8 + 2*j]),     0.0f);
            float hi = fmaxf(fmaf(dv, a0[2*j+1] + a1[2*j+1] + a2[2*j+1] + a3[2*j+1], b[f8 + 2*j + 1]), 0.0f);
            unsigned int ul = (unsigned int)__bfloat16_as_ushort(__float2bfloat16(lo));
            unsigned int uh = (unsigned int)__bfloat16_as_ushort(__float2bfloat16(hi));
            pk[j] = ul | (uh << 16);
        }
        uint4 st = make_uint4(pk[0], pk[1], pk[2], pk[3]);
        *(uint4*)((unsigned short*)xout + (size_t)node * DIMF + f8) = st;
    }
}

__device__ void head_phase(
    const unsigned int* __restrict__ x,     // bf16x2 packed, 32 uints/row
    const float* __restrict__ Wp1, const float* __restrict__ bp1,
    const float* __restrict__ Wp2, const float* __restrict__ bp2,
    float* __restrict__ out, int n, float* sm)
{
    float* W1s = sm;            // 2048
    float* W2s = sm + 2048;     // 1280
    float* b1s = sm + 3328;     // 32
    float* b2s = sm + 3360;     // 40
    int t = threadIdx.x;
    for (int i = t; i < 2048; i += 256) W1s[i] = Wp1[i];
    for (int i = t; i < 1280; i += 256) W2s[i] = Wp2[i];
    if (t < 32) b1s[t] = bp1[t];
    if (t < 40) b2s[t] = bp2[t];
    __syncthreads();
    int nchunk = (n + 255) >> 8;
    for (int c = blockIdx.x; c < nchunk; c += gridDim.x) {
        int node = (c << 8) + t;
        if (node >= n) continue;

        const uint4* xp = (const uint4*)(x + (size_t)node * 32);
        float h[32];
#pragma unroll
        for (int j = 0; j < 32; j++) h[j] = b1s[j];
#pragma unroll
        for (int k8 = 0; k8 < 8; k8++) {
            uint4 v = xp[k8];
            float xv[8];
            xv[0] = __uint_as_float(v.x << 16);
            xv[1] = __uint_as_float(v.x & 0xffff0000u);
            xv[2] = __uint_as_float(v.y << 16);
            xv[3] = __uint_as_float(v.y & 0xffff0000u);
            xv[4] = __uint_as_float(v.z << 16);
            xv[5] = __uint_as_float(v.z & 0xffff0000u);
            xv[6] = __uint_as_float(v.w << 16);
            xv[7] = __uint_as_float(v.w & 0xffff0000u);
            int k = k8 << 3;
#pragma unroll
            for (int kk = 0; kk < 8; kk++)
#pragma unroll
                for (int j = 0; j < 32; j++)
                    h[j] = fmaf(xv[kk], W1s[(k + kk) * 32 + j], h[j]);
        }
#pragma unroll
        for (int j = 0; j < 32; j++) h[j] = h[j] > 0.0f ? h[j] : 0.0f;

        float o[40];
#pragma unroll
        for (int j = 0; j < 40; j++) o[j] = b2s[j];
        for (int k = 0; k < 32; k++) {
            float hv = h[k];
#pragma unroll
            for (int j = 0; j < 40; j++) o[j] = fmaf(hv, W2s[k * 40 + j], o[j]);
        }
        float m = o[0];
#pragma unroll
        for (int j = 1; j < 40; j++) m = fmaxf(m, o[j]);
        float sum = 0.0f;
#pragma unroll
        for (int j = 0; j < 40; j++) sum += expf(o[j] - m);
        float lse = logf(sum) + m;
        float* op = out + (size_t)node * 40;
#pragma unroll
        for (int j = 0; j < 40; j++) op[j] = o[j] - lse;
    }
}

__global__ __launch_bounds__(256, 4) void fused_gnn(FusedArgs a)
{
    cg::grid_group grid = cg::this_grid();
    __shared__ float sWs[4096];
    __shared__ float sXs[32][65];

    gemm_f32(a.x, a.W0, a.dinv, a.hp, a.n, sWs, sXs);
    grid.sync();
    gather_phase((const unsigned int*)a.hp, a.row_start, a.csr_src, a.dinv, a.b0, a.xbuf, a.n);
    grid.sync();
    gemm_bf16((const unsigned int*)a.xbuf, a.W1, a.dinv, a.hp, a.n, sWs, sXs);
    grid.sync();
    gather_phase((const unsigned int*)a.hp, a.row_start, a.csr_src, a.dinv, a.b1, a.xbuf, a.n);
    grid.sync();
    gemm_bf16((const unsigned int*)a.xbuf, a.W2, a.dinv, a.hp, a.n, sWs, sXs);
    grid.sync();
    gather_phase((const unsigned int*)a.hp, a.row_start, a.csr_src, a.dinv, a.b2, a.xbuf, a.n);
    grid.sync();
    head_phase((const unsigned int*)a.xbuf, a.Wp1, a.bp1, a.Wp2, a.bp2, a.out, a.n, sWs);
}

extern "C" void kernel_launch(void* const* d_in, const int* in_sizes, int n_in,
                              void* d_out, int out_size, void* d_ws, size_t ws_size,
                              hipStream_t stream)
{
    const float* x  = (const float*)d_in[0];
    const int*   ei = (const int*)d_in[1];
    const int E = in_sizes[1] / 2;
    const int n = in_sizes[0] / DIMF;
    const int* src = ei;
    const int* dst = ei + E;
    float* out = (float*)d_out;

    const int NBK  = (n + 511) >> BSH;            // buckets (<= 256)
    const int tile = (E + NBA - 1) / NBA;

    // Workspace: partial[NBA*256] | bucket_off[257] | gcursor[256] |
    //            row_start[n+1] | dinv[n] | csr_src[E] | hp[n*64 bf16] |
    //            xbuf[n*64 bf16]  (ebuf[E uint] aliases xbuf)
    char* p = (char*)d_ws;
    int* partial    = (int*)p;                p += (size_t)NBA * 256 * 4;
    int* bucket_off = (int*)p;                p += 257 * 4;
    int* gcursor    = (int*)p;                p += 256 * 4;
    p = (char*)(((size_t)p + 15) & ~(size_t)15);
    int* row_start  = (int*)p;                p += (size_t)(n + 1) * 4;
    float* dinv     = (float*)p;              p += (size_t)n * 4;
    p = (char*)(((size_t)p + 15) & ~(size_t)15);
    int* csr_src    = (int*)p;                p += (size_t)E * 4;
    p = (char*)(((size_t)p + 15) & ~(size_t)15);
    __hip_bfloat16* hp = (__hip_bfloat16*)p;  p += (size_t)n * DIMF * 2;
    p = (char*)(((size_t)p + 15) & ~(size_t)15);
    __hip_bfloat16* xbuf = (__hip_bfloat16*)p;
    unsigned int* ebuf   = (unsigned int*)xbuf;   // dead once gather0 runs

    // --- CSR build (bucketed, LDS-heavy, packed ebuf) ---
    hipLaunchKernelGGL(bucket_count,   dim3(NBA), dim3(256), 0, stream, dst, partial, E, tile);
    hipLaunchKernelGGL(bucket_scan,    dim3(1),   dim3(256), 0, stream, partial, bucket_off, gcursor, NBA);
    hipLaunchKernelGGL(bucket_scatter, dim3(NBA), dim3(256), 0, stream, src, dst, gcursor, ebuf, E, tile);
    hipLaunchKernelGGL(bucket_csr,     dim3(NBK), dim3(256), 0, stream, ebuf, bucket_off,
                       row_start, csr_src, dinv, n, E);

    // --- fused 3 layers + head (cooperative, 6 grid syncs) ---
    FusedArgs fa;
    fa.x = x; fa.row_start = row_start; fa.csr_src = csr_src; fa.dinv = dinv;
    fa.W0 = (const float*)d_in[3];  fa.b0 = (const float*)d_in[4];
    fa.W1 = (const float*)d_in[5];  fa.b1 = (const float*)d_in[6];
    fa.W2 = (const float*)d_in[7];  fa.b2 = (const float*)d_in[8];
    fa.Wp1 = (const float*)d_in[9]; fa.bp1 = (const float*)d_in[10];
    fa.Wp2 = (const float*)d_in[11];fa.bp2 = (const float*)d_in[12];
    fa.out = out; fa.hp = hp; fa.xbuf = xbuf; fa.n = n;

    int maxBlocksPerCU = 0;
    hipOccupancyMaxActiveBlocksPerMultiprocessor(&maxBlocksPerCU, fused_gnn, 256, 0);
    if (maxBlocksPerCU < 1) maxBlocksPerCU = 1;
    int grid = maxBlocksPerCU * 256;   // 256 CUs on MI355X
    if (grid > 1024) grid = 1024;

    void* kargs[] = { (void*)&fa };
    hipLaunchCooperativeKernel((const void*)fused_gnn, dim3(grid), dim3(256),
                               kargs, 0, stream);
}

// Round 12
// 430.388 us; speedup vs baseline: 2.4395x; 2.4395x over previous
//
#include <hip/hip_runtime.h>
#include <hip/hip_bf16.h>
#include <math.h>

// GCN stack: 3x [GCNConv + ReLU] + MLP head (64->32 relu ->40) + log_softmax.
// R12: pairwise fusion along data-flow seams (R11 post-mortem: whole-pipeline
// cooperative fusion spilled — 64-VGPR cap vs 88-VGPR phases, WRITE 363MB).
// gather(l) output row i feeds only gemm(l+1) row i -> same block:
//   K0 = gemm0, K1/K2 = gather+gemm (f32 through LDS, no xbuf),
//   K3 = gather+MLP-head (8 lanes/node, shfl folds). hp double-buffered.
// CSR: packed 4B ebuf; bucket_scatter reuses bucket_count's partial.

#define DIMF 64
#define NBA  200     // blocks for bucket count/scatter
#define BSH  9       // 512 nodes per bucket

// ---------------- CSR build (bucketed, packed ebuf) ----------------

__global__ __launch_bounds__(256) void bucket_count(
    const int* __restrict__ dst, int* __restrict__ partial, int E, int tile)
{
    __shared__ int h[256];
    int t = threadIdx.x;
    h[t] = 0;
    __syncthreads();
    int estart = blockIdx.x * tile;
    int eend = min(E, estart + tile);
    for (int e = estart + t; e < eend; e += 256)
        atomicAdd(&h[dst[e] >> BSH], 1);
    __syncthreads();
    partial[blockIdx.x * 256 + t] = h[t];
}

__global__ __launch_bounds__(256) void bucket_scan(
    const int* __restrict__ partial, int* __restrict__ bucket_off,
    int* __restrict__ gcursor, int nba)
{
    __shared__ int s[256];
    int t = threadIdx.x;
    int sum = 0;
    for (int b = 0; b < nba; b++) sum += partial[b * 256 + t];
    s[t] = sum;
    __syncthreads();
    for (int off = 1; off < 256; off <<= 1) {
        int v = (t >= off) ? s[t - off] : 0;
        __syncthreads();
        s[t] += v;
        __syncthreads();
    }
    int excl = s[t] - sum;
    bucket_off[t] = excl;
    gcursor[t] = excl;
    if (t == 255) bucket_off[256] = s[t];   // == E
}

__global__ __launch_bounds__(256) void bucket_scatter(
    const int* __restrict__ src, const int* __restrict__ dst,
    const int* __restrict__ partial, int* __restrict__ gcursor,
    unsigned int* __restrict__ ebuf, int E, int tile)
{
    __shared__ int h[256];
    int t = threadIdx.x;
    // reuse bucket_count's histogram instead of re-counting
    h[t] = atomicAdd(&gcursor[t], partial[blockIdx.x * 256 + t]);
    __syncthreads();
    int estart = blockIdx.x * tile;
    int eend = min(E, estart + tile);
    for (int e = estart + t; e < eend; e += 256) {
        int d = dst[e];
        int p = atomicAdd(&h[d >> BSH], 1);
        ebuf[p] = ((unsigned int)src[e] << BSH) | (unsigned int)(d & 511);
    }
}

__global__ __launch_bounds__(256) void bucket_csr(
    const unsigned int* __restrict__ ebuf, const int* __restrict__ bucket_off,
    int* __restrict__ row_start, int* __restrict__ csr_src,
    float* __restrict__ dinv, int n, int E)
{
    __shared__ int cnt[512];
    __shared__ int ps[256];
    int t = threadIdx.x;
    int blk = blockIdx.x;
    int node0 = blk << BSH;
    cnt[t] = 0; cnt[t + 256] = 0;
    __syncthreads();
    int bs = bucket_off[blk], be = bucket_off[blk + 1];
    for (int i = bs + t; i < be; i += 256)
        atomicAdd(&cnt[ebuf[i] & 511], 1);
    __syncthreads();
    int c0 = cnt[2 * t], c1 = cnt[2 * t + 1];
    ps[t] = c0 + c1;
    __syncthreads();
    for (int off = 1; off < 256; off <<= 1) {
        int v = (t >= off) ? ps[t - off] : 0;
        __syncthreads();
        ps[t] += v;
        __syncthreads();
    }
    int pexcl = ps[t] - (c0 + c1);
    int e0 = pexcl, e1 = pexcl + c0;
    int g0 = node0 + 2 * t, g1 = g0 + 1;
    if (g0 < n) { row_start[g0] = bs + e0; dinv[g0] = rsqrtf((float)c0 + 1.0f); }
    if (g1 < n) { row_start[g1] = bs + e1; dinv[g1] = rsqrtf((float)c1 + 1.0f); }
    __syncthreads();
    cnt[2 * t] = e0; cnt[2 * t + 1] = e1;    // cnt becomes local cursor
    __syncthreads();
    for (int i = bs + t; i < be; i += 256) {
        unsigned int pk = ebuf[i];
        int p = bs + atomicAdd(&cnt[pk & 511], 1);
        csr_src[p] = (int)(pk >> BSH);
    }
    if (blk == gridDim.x - 1 && t == 0) row_start[n] = E;
}

// ---------------- K0: gemm0 (f32 x -> hpA bf16) ----------------

__global__ __launch_bounds__(256) void gemm_scale_f32(
    const float* __restrict__ xin, const float* __restrict__ W,
    const float* __restrict__ dinv, __hip_bfloat16* __restrict__ hprime, int n)
{
    __shared__ float Ws[64 * 64];
    __shared__ float Xs[32][65];
    int t = threadIdx.x;
    for (int i = t; i < 4096; i += 256) Ws[i] = W[i];
    int row0 = blockIdx.x * 32;
    for (int i = t; i < 2048; i += 256) {
        int r = i >> 6, c = i & 63;
        int gr = row0 + r;
        Xs[r][c] = (gr < n) ? xin[(size_t)gr * DIMF + c] : 0.0f;
    }
    __syncthreads();
    int col = t & 63;
    int rbase = (t >> 6) * 8;
    float av[8];
#pragma unroll
    for (int rr = 0; rr < 8; rr++) av[rr] = 0.0f;
    for (int k = 0; k < 64; k++) {
        float w = Ws[k * 64 + col];
#pragma unroll
        for (int rr = 0; rr < 8; rr++)
            av[rr] = fmaf(Xs[rbase + rr][k], w, av[rr]);
    }
#pragma unroll
    for (int rr = 0; rr < 8; rr++) {
        int gr = row0 + rbase + rr;
        if (gr < n)
            hprime[(size_t)gr * DIMF + col] = __float2bfloat16(av[rr] * dinv[gr]);
    }
}

// ---------------- shared gather body (R10: 4-deep unroll) ----------------
// Returns this lane's 8 post-epilogue features xv[0..7] (f32).
// lane layout: slot = lane>>3 (node within octet), o = lane&7 (feature oct).

#define GATHER_BODY(xv_out)                                                    \
    float xv_out[8];                                                           \
    {                                                                          \
        int rs = row_start[node];                                              \
        int re = row_start[node + 1];                                          \
        int deg = re - rs;                                                     \
        float a0[8], a1[8], a2[8], a3[8];                                      \
        _Pragma("unroll")                                                      \
        for (int i = 0; i < 8; i++) { a0[i]=0.f; a1[i]=0.f; a2[i]=0.f; a3[i]=0.f; } \
        {                                                                      \
            uint4 v = *(const uint4*)(hprime + (size_t)node * 32 + uoff);      \
            ADDROW(a0, v);                                                     \
        }                                                                      \
        int k = 0;                                                             \
        if (deg >= 4) {                                                        \
            int i0 = csr_src[rs], i1 = csr_src[rs + 1];                        \
            int i2 = csr_src[rs + 2], i3 = csr_src[rs + 3];                    \
            for (; k + 4 <= deg; k += 4) {                                     \
                int m0 = (k + 4 < deg) ? csr_src[rs + k + 4] : 0;              \
                int m1 = (k + 5 < deg) ? csr_src[rs + k + 5] : 0;              \
                int m2 = (k + 6 < deg) ? csr_src[rs + k + 6] : 0;              \
                int m3 = (k + 7 < deg) ? csr_src[rs + k + 7] : 0;              \
                uint4 v0 = *(const uint4*)(hprime + (size_t)i0 * 32 + uoff);   \
                uint4 v1 = *(const uint4*)(hprime + (size_t)i1 * 32 + uoff);   \
                uint4 v2 = *(const uint4*)(hprime + (size_t)i2 * 32 + uoff);   \
                uint4 v3 = *(const uint4*)(hprime + (size_t)i3 * 32 + uoff);   \
                ADDROW(a0, v0); ADDROW(a1, v1); ADDROW(a2, v2); ADDROW(a3, v3);\
                i0 = m0; i1 = m1; i2 = m2; i3 = m3;                            \
            }                                                                  \
        }                                                                      \
        for (; k < deg; k++) {                                                 \
            int idx = csr_src[rs + k];                                         \
            uint4 v = *(const uint4*)(hprime + (size_t)idx * 32 + uoff);       \
            ADDROW(a0, v);                                                     \
        }                                                                      \
        int f8 = uoff << 1;                                                    \
        float dv = dinv[node];                                                 \
        _Pragma("unroll")                                                      \
        for (int j = 0; j < 8; j++)                                            \
            xv_out[j] = fmaxf(fmaf(dv, a0[j] + a1[j] + a2[j] + a3[j],          \
                                   b[f8 + j]), 0.0f);                          \
    }

#define ADDROW(a, v)                                                       \
    {                                                                      \
        a[0] += __uint_as_float((v).x << 16);                              \
        a[1] += __uint_as_float((v).x & 0xffff0000u);                      \
        a[2] += __uint_as_float((v).y << 16);                              \
        a[3] += __uint_as_float((v).y & 0xffff0000u);                      \
        a[4] += __uint_as_float((v).z << 16);                              \
        a[5] += __uint_as_float((v).z & 0xffff0000u);                      \
        a[6] += __uint_as_float((v).w << 16);                              \
        a[7] += __uint_as_float((v).w & 0xffff0000u);                      \
    }

// ---------------- K1/K2: gather(l) + gemm(l+1), f32 through LDS ----------

__global__ __launch_bounds__(256) void gather_gemm(
    const unsigned int* __restrict__ hprime,  // hp(l) bf16x2, 32 uints/row
    const int* __restrict__ row_start, const int* __restrict__ csr_src,
    const float* __restrict__ dinv, const float* __restrict__ b,   // b(l)
    const float* __restrict__ Wn,                                  // W(l+1)
    __hip_bfloat16* __restrict__ hpout, int n)
{
    __shared__ float Ws[64 * 64];   // 16 KB
    __shared__ float Xs[32][65];    // 8.3 KB
    int t = threadIdx.x;
    for (int i = t; i < 4096; i += 256) Ws[i] = Wn[i];

    int wave = t >> 6;
    int lane = t & 63;
    int slot = lane >> 3;
    int o    = lane & 7;
    int uoff = o << 2;
    int ln   = (wave << 3) + slot;          // local node 0..31
    int row0 = blockIdx.x * 32;
    int node = row0 + ln;

    if (node < n) {
        GATHER_BODY(xv)
        int f8 = o << 3;
#pragma unroll
        for (int j = 0; j < 8; j++) Xs[ln][f8 + j] = xv[j];
    } else {
        int f8 = o << 3;
#pragma unroll
        for (int j = 0; j < 8; j++) Xs[ln][f8 + j] = 0.0f;
    }
    __syncthreads();

    int col = t & 63;
    int rbase = (t >> 6) * 8;
    float av[8];
#pragma unroll
    for (int rr = 0; rr < 8; rr++) av[rr] = 0.0f;
    for (int k = 0; k < 64; k++) {
        float w = Ws[k * 64 + col];
#pragma unroll
        for (int rr = 0; rr < 8; rr++)
            av[rr] = fmaf(Xs[rbase + rr][k], w, av[rr]);
    }
#pragma unroll
    for (int rr = 0; rr < 8; rr++) {
        int gr = row0 + rbase + rr;
        if (gr < n)
            hpout[(size_t)gr * DIMF + col] = __float2bfloat16(av[rr] * dinv[gr]);
    }
}

// ---------------- K3: gather(2) + MLP head + log_softmax ------------------
// 8 lanes/node cooperative head: partial h over 8 feats -> shfl_xor(1,2,4)
// fold -> relu -> each lane computes 5 of 40 outputs -> shfl softmax.

__global__ __launch_bounds__(256) void gather_head(
    const unsigned int* __restrict__ hprime,  // hp(2) bf16x2
    const int* __restrict__ row_start, const int* __restrict__ csr_src,
    const float* __restrict__ dinv, const float* __restrict__ b,   // b(2)
    const float* __restrict__ Wp1, const float* __restrict__ bp1,
    const float* __restrict__ Wp2, const float* __restrict__ bp2,
    float* __restrict__ out, int n)
{
    __shared__ float W1s[64 * 33];   // stride 33: breaks 8-way bank conflict
    __shared__ float W2s[32 * 40];
    __shared__ float b1s[32], b2s[40];
    int t = threadIdx.x;
    for (int i = t; i < 2048; i += 256) {
        int k = i >> 5, c = i & 31;
        W1s[k * 33 + c] = Wp1[i];
    }
    for (int i = t; i < 1280; i += 256) W2s[i] = Wp2[i];
    if (t < 32) b1s[t] = bp1[t];
    if (t < 40) b2s[t] = bp2[t];
    __syncthreads();

    int wave = t >> 6;
    int lane = t & 63;
    int slot = lane >> 3;
    int o    = lane & 7;
    int uoff = o << 2;
    int node = blockIdx.x * 32 + (wave << 3) + slot;
    if (node >= n) return;

    GATHER_BODY(xv)

    // partial h[32] from this lane's 8 features
    float hp[32];
#pragma unroll
    for (int c = 0; c < 32; c++) hp[c] = 0.0f;
#pragma unroll
    for (int j = 0; j < 8; j++) {
        float xj = xv[j];
        const float* wrow = W1s + (o * 8 + j) * 33;
#pragma unroll
        for (int c = 0; c < 32; c++) hp[c] = fmaf(xj, wrow[c], hp[c]);
    }
    // fold across the 8 lanes of this node
#pragma unroll
    for (int mask = 1; mask <= 4; mask <<= 1)
#pragma unroll
        for (int c = 0; c < 32; c++) hp[c] += __shfl_xor(hp[c], mask);
#pragma unroll
    for (int c = 0; c < 32; c++) hp[c] = fmaxf(hp[c] + b1s[c], 0.0f);

    // each lane computes 5 of the 40 logits
    float oo[5];
#pragma unroll
    for (int m = 0; m < 5; m++) {
        int j5 = o * 5 + m;
        float acc = b2s[j5];
#pragma unroll
        for (int k = 0; k < 32; k++) acc = fmaf(hp[k], W2s[k * 40 + j5], acc);
        oo[m] = acc;
    }
    float mx = oo[0];
#pragma unroll
    for (int m = 1; m < 5; m++) mx = fmaxf(mx, oo[m]);
#pragma unroll
    for (int mask = 1; mask <= 4; mask <<= 1) mx = fmaxf(mx, __shfl_xor(mx, mask));
    float se = 0.0f;
#pragma unroll
    for (int m = 0; m < 5; m++) se += expf(oo[m] - mx);
#pragma unroll
    for (int mask = 1; mask <= 4; mask <<= 1) se += __shfl_xor(se, mask);
    float lse = logf(se) + mx;
    float* op = out + (size_t)node * 40 + o * 5;
#pragma unroll
    for (int m = 0; m < 5; m++) op[m] = oo[m] - lse;
}

extern "C" void kernel_launch(void* const* d_in, const int* in_sizes, int n_in,
                              void* d_out, int out_size, void* d_ws, size_t ws_size,
                              hipStream_t stream)
{
    const float* x  = (const float*)d_in[0];
    const int*   ei = (const int*)d_in[1];
    const int E = in_sizes[1] / 2;
    const int n = in_sizes[0] / DIMF;
    const int* src = ei;
    const int* dst = ei + E;
    const float* W0 = (const float*)d_in[3];  const float* b0 = (const float*)d_in[4];
    const float* W1 = (const float*)d_in[5];  const float* b1 = (const float*)d_in[6];
    const float* W2 = (const float*)d_in[7];  const float* b2 = (const float*)d_in[8];
    const float* Wp1 = (const float*)d_in[9];  const float* bp1 = (const float*)d_in[10];
    const float* Wp2 = (const float*)d_in[11]; const float* bp2 = (const float*)d_in[12];
    float* out = (float*)d_out;

    const int NBK  = (n + 511) >> BSH;            // buckets (<= 256)
    const int tile = (E + NBA - 1) / NBA;

    // Workspace: partial[NBA*256] | bucket_off[257] | gcursor[256] |
    //            row_start[n+1] | dinv[n] | csr_src[E] |
    //            hpA[n*64 bf16] | hpB[n*64 bf16]  (ebuf[E uint] aliases hpB)
    char* p = (char*)d_ws;
    int* partial    = (int*)p;                p += (size_t)NBA * 256 * 4;
    int* bucket_off = (int*)p;                p += 257 * 4;
    int* gcursor    = (int*)p;                p += 256 * 4;
    p = (char*)(((size_t)p + 15) & ~(size_t)15);
    int* row_start  = (int*)p;                p += (size_t)(n + 1) * 4;
    float* dinv     = (float*)p;              p += (size_t)n * 4;
    p = (char*)(((size_t)p + 15) & ~(size_t)15);
    int* csr_src    = (int*)p;                p += (size_t)E * 4;
    p = (char*)(((size_t)p + 15) & ~(size_t)15);
    __hip_bfloat16* hpA = (__hip_bfloat16*)p; p += (size_t)n * DIMF * 2;
    p = (char*)(((size_t)p + 15) & ~(size_t)15);
    __hip_bfloat16* hpB = (__hip_bfloat16*)p;
    unsigned int* ebuf  = (unsigned int*)hpB;  // dead once K1 writes hpB

    const int nblk = (n + 31) / 32;

    // --- CSR build ---
    hipLaunchKernelGGL(bucket_count,   dim3(NBA), dim3(256), 0, stream, dst, partial, E, tile);
    hipLaunchKernelGGL(bucket_scan,    dim3(1),   dim3(256), 0, stream, partial, bucket_off, gcursor, NBA);
    hipLaunchKernelGGL(bucket_scatter, dim3(NBA), dim3(256), 0, stream, src, dst, partial, gcursor, ebuf, E, tile);
    hipLaunchKernelGGL(bucket_csr,     dim3(NBK), dim3(256), 0, stream, ebuf, bucket_off,
                       row_start, csr_src, dinv, n, E);

    // --- fused pipeline: K0, K1, K2, K3 ---
    hipLaunchKernelGGL(gemm_scale_f32, dim3(nblk), dim3(256), 0, stream,
                       x, W0, dinv, hpA, n);
    hipLaunchKernelGGL(gather_gemm, dim3(nblk), dim3(256), 0, stream,
                       (const unsigned int*)hpA, row_start, csr_src, dinv, b0,
                       W1, hpB, n);
    hipLaunchKernelGGL(gather_gemm, dim3(nblk), dim3(256), 0, stream,
                       (const unsigned int*)hpB, row_start, csr_src, dinv, b1,
                       W2, hpA, n);
    hipLaunchKernelGGL(gather_head, dim3(nblk), dim3(256), 0, stream,
                       (const unsigned int*)hpA, row_start, csr_src, dinv, b2,
                       Wp1, bp1, Wp2, bp2, out, n);
}